// Round 1
// baseline (118.923 us; speedup 1.0000x reference)
//
#include <hip/hip_runtime.h>

// GCNConv: out[i] = deg[i] * sum_{e in [rp[i],rp[i+1])} deg[ci[e]] * (X @ W)[ci[e]]
// Split: (1) GEMM with fused per-row deg scale -> Xp in workspace
//        (2) CSR gather-sum with final deg scale -> out

constexpr int D_IN  = 256;
constexpr int D_OUT = 64;
constexpr int TM    = 64;   // rows per block tile
constexpr int KC    = 64;   // k-chunk staged in LDS
constexpr int XS_LD = KC + 4;  // pad to 68 floats = 272B row stride (16B aligned, bank-spread)

__global__ __launch_bounds__(256) void gemm_scale_kernel(
    const float* __restrict__ X, const float* __restrict__ W,
    const float* __restrict__ deg, float* __restrict__ Xp, int n)
{
    __shared__ float Xs[TM][XS_LD];   // [row][k]  ~17.4 KB
    __shared__ float Ws[KC][D_OUT];   // [k][col]   16 KB

    const int tid  = threadIdx.x;
    const int row0 = blockIdx.x * TM;
    const int rg   = tid >> 4;   // 0..15 -> rows rg*4 .. rg*4+3
    const int cg   = tid & 15;   // 0..15 -> cols cg*4 .. cg*4+3

    float acc[4][4] = {};

    for (int k0 = 0; k0 < D_IN; k0 += KC) {
        const int kk = tid & 63;   // lane-contiguous k for coalesced global reads
        const int q  = tid >> 6;   // 0..3
        #pragma unroll
        for (int i = 0; i < 16; ++i) {
            const int r = q + i * 4;
            int gr = row0 + r;
            if (gr >= n) gr = n - 1;            // clamp (safe read), store is guarded
            Xs[r][kk] = X[(size_t)gr * D_IN + k0 + kk];
        }
        #pragma unroll
        for (int i = 0; i < 16; ++i) {
            const int kr = q + i * 4;
            Ws[kr][kk] = W[(size_t)(k0 + kr) * D_OUT + kk];
        }
        __syncthreads();

        #pragma unroll
        for (int kk4 = 0; kk4 < KC; kk4 += 4) {
            float4 xv[4];
            float4 wv[4];
            #pragma unroll
            for (int r = 0; r < 4; ++r)
                xv[r] = *reinterpret_cast<const float4*>(&Xs[rg * 4 + r][kk4]);
            #pragma unroll
            for (int k = 0; k < 4; ++k)
                wv[k] = *reinterpret_cast<const float4*>(&Ws[kk4 + k][cg * 4]);
            #pragma unroll
            for (int r = 0; r < 4; ++r) {
                const float xr[4] = {xv[r].x, xv[r].y, xv[r].z, xv[r].w};
                #pragma unroll
                for (int k = 0; k < 4; ++k) {
                    acc[r][0] += xr[k] * wv[k].x;
                    acc[r][1] += xr[k] * wv[k].y;
                    acc[r][2] += xr[k] * wv[k].z;
                    acc[r][3] += xr[k] * wv[k].w;
                }
            }
        }
        __syncthreads();
    }

    #pragma unroll
    for (int r = 0; r < 4; ++r) {
        const int grow = row0 + rg * 4 + r;
        if (grow < n) {
            const float d = deg[grow];   // fold deg[j] into X' rows
            float4 v = make_float4(acc[r][0] * d, acc[r][1] * d,
                                   acc[r][2] * d, acc[r][3] * d);
            *reinterpret_cast<float4*>(&Xp[(size_t)grow * D_OUT + cg * 4]) = v;
        }
    }
}

__global__ __launch_bounds__(256) void agg_kernel(
    const float* __restrict__ Xp, const int* __restrict__ rp,
    const int* __restrict__ ci, const float* __restrict__ deg,
    float* __restrict__ out, int n)
{
    const int node = blockIdx.x * 4 + (threadIdx.x >> 6);  // 4 nodes / block
    const int c    = threadIdx.x & 63;                     // lane = output column
    if (node >= n) return;

    const int e0 = rp[node];
    const int e1 = rp[node + 1];

    float acc = 0.0f;
    int e = e0;
    for (; e + 4 <= e1; e += 4) {      // 4-way index prefetch for MLP
        const int j0 = ci[e + 0];
        const int j1 = ci[e + 1];
        const int j2 = ci[e + 2];
        const int j3 = ci[e + 3];
        acc += Xp[(size_t)j0 * D_OUT + c];
        acc += Xp[(size_t)j1 * D_OUT + c];
        acc += Xp[(size_t)j2 * D_OUT + c];
        acc += Xp[(size_t)j3 * D_OUT + c];
    }
    for (; e < e1; ++e)
        acc += Xp[(size_t)ci[e] * D_OUT + c];

    out[(size_t)node * D_OUT + c] = acc * deg[node];
}

extern "C" void kernel_launch(void* const* d_in, const int* in_sizes, int n_in,
                              void* d_out, int out_size, void* d_ws, size_t ws_size,
                              hipStream_t stream)
{
    const float* X   = (const float*)d_in[0];
    const float* W   = (const float*)d_in[1];
    const int*   rp  = (const int*)d_in[2];
    const int*   ci  = (const int*)d_in[3];
    const float* deg = (const float*)d_in[4];
    float* out = (float*)d_out;
    float* Xp  = (float*)d_ws;   // n * D_OUT floats = 25.6 MB

    const int n = in_sizes[4];   // N_NODES (degrees element count)

    const int gemm_blocks = (n + TM - 1) / TM;
    gemm_scale_kernel<<<gemm_blocks, 256, 0, stream>>>(X, W, deg, Xp, n);

    const int agg_blocks = (n + 3) / 4;
    agg_kernel<<<agg_blocks, 256, 0, stream>>>(Xp, rp, ci, deg, out, n);
}

// Round 2
// 57.320 us; speedup vs baseline: 2.0747x; 2.0747x over previous
//
#include <hip/hip_runtime.h>
#include <hip/hip_bf16.h>

// GCN: out[i] = deg_i * sum_{j in N(i)} deg_j * (X@W)[j]
// K1: bf16-MFMA GEMM, fused deg_j scale, Xp stored bf16 in ws.
//     Operand-swapped: D = (W^T)*(X^T) so each lane owns 4 consecutive
//     output cols of one node row -> bf16x4 packed stores.
// K2: CSR gather-sum over bf16 Xp (8 lanes/node, 16B/lane), final deg_i scale.

constexpr int D_IN  = 256;
constexpr int D_OUT = 64;
constexpr int WT_LD = D_IN + 8;   // 264 bf16 = 528B row stride (16B-aligned, 2-way banks)

typedef short  s8v  __attribute__((ext_vector_type(8)));
typedef __bf16 bf8v __attribute__((ext_vector_type(8)));
typedef float  f32x4 __attribute__((ext_vector_type(4)));
typedef unsigned short us8v __attribute__((ext_vector_type(8)));

union BF8 { bf8v b; s8v s; };

__global__ __launch_bounds__(256) void gemm_bf16_kernel(
    const float* __restrict__ X, const float* __restrict__ W,
    const float* __restrict__ deg, unsigned short* __restrict__ Xp, int n)
{
    __shared__ __bf16 Wt[D_OUT][WT_LD];   // W transposed: Wt[c][k], 33792 B

    const int tid = threadIdx.x;

    // Stage W (256x64 fp32) -> Wt bf16, transposed. One-time per block.
    #pragma unroll
    for (int i = 0; i < 16; ++i) {
        const int f4 = tid + i * 256;          // float4 index into W
        const int k  = f4 >> 4;
        const int c4 = (f4 & 15) * 4;
        const float4 w = *reinterpret_cast<const float4*>(&W[(size_t)k * D_OUT + c4]);
        Wt[c4 + 0][k] = (__bf16)w.x;
        Wt[c4 + 1][k] = (__bf16)w.y;
        Wt[c4 + 2][k] = (__bf16)w.z;
        Wt[c4 + 3][k] = (__bf16)w.w;
    }
    __syncthreads();

    const int wid  = tid >> 6;
    const int lane = tid & 63;
    const int lrow = lane & 15;     // node row within 16-chunk / Wt col within group
    const int kgrp = lane >> 4;     // 0..3

    const int row0 = blockIdx.x * 64 + wid * 16;
    if (row0 >= n) return;
    const int grow = row0 + lrow;
    const int xr   = grow < n ? grow : n - 1;   // clamped load row

    f32x4 acc[4] = {};  // frag f covers output cols f*16 + kgrp*4 + 0..3

    const float* xrow = X + (size_t)xr * D_IN + kgrp * 8;
    const __bf16* wt0 = &Wt[lrow][kgrp * 8];    // frag f at +f*16 rows

    #pragma unroll
    for (int ks = 0; ks < 8; ++ks) {
        const int k0 = ks * 32;
        // B-operand: X^T fragment — 8 consecutive fp32 from this lane's row
        const float4 x0 = *reinterpret_cast<const float4*>(xrow + k0);
        const float4 x1 = *reinterpret_cast<const float4*>(xrow + k0 + 4);
        BF8 xf;
        xf.b[0] = (__bf16)x0.x; xf.b[1] = (__bf16)x0.y;
        xf.b[2] = (__bf16)x0.z; xf.b[3] = (__bf16)x0.w;
        xf.b[4] = (__bf16)x1.x; xf.b[5] = (__bf16)x1.y;
        xf.b[6] = (__bf16)x1.z; xf.b[7] = (__bf16)x1.w;

        #pragma unroll
        for (int f = 0; f < 4; ++f) {
            // A-operand: Wt fragment — 16B contiguous from LDS
            const s8v wf = *reinterpret_cast<const s8v*>(wt0 + (size_t)f * 16 * WT_LD + k0);
            acc[f] = __builtin_amdgcn_mfma_f32_16x16x32_bf16(wf, xf.s, acc[f], 0, 0, 0);
        }
    }

    if (grow < n) {
        const float d = deg[grow];   // fold deg_j into Xp rows
        #pragma unroll
        for (int f = 0; f < 4; ++f) {
            ushort4 v;
            __bf16 b0 = (__bf16)(acc[f][0] * d);
            __bf16 b1 = (__bf16)(acc[f][1] * d);
            __bf16 b2 = (__bf16)(acc[f][2] * d);
            __bf16 b3 = (__bf16)(acc[f][3] * d);
            v.x = *reinterpret_cast<unsigned short*>(&b0);
            v.y = *reinterpret_cast<unsigned short*>(&b1);
            v.z = *reinterpret_cast<unsigned short*>(&b2);
            v.w = *reinterpret_cast<unsigned short*>(&b3);
            *reinterpret_cast<ushort4*>(
                &Xp[(size_t)grow * D_OUT + f * 16 + kgrp * 4]) = v;
        }
    }
}

__global__ __launch_bounds__(256) void agg_kernel(
    const unsigned short* __restrict__ Xp, const int* __restrict__ rp,
    const int* __restrict__ ci, const float* __restrict__ deg,
    float* __restrict__ out, int n)
{
    const int node = blockIdx.x * 32 + (threadIdx.x >> 3);  // 32 nodes/block
    if (node >= n) return;
    const int c8 = (threadIdx.x & 7) * 8;                   // 8 cols/thread

    const int e0 = rp[node];
    const int e1 = rp[node + 1];

    float acc[8] = {};
    int e = e0;
    for (; e + 4 <= e1; e += 4) {
        const int j0 = ci[e + 0];
        const int j1 = ci[e + 1];
        const int j2 = ci[e + 2];
        const int j3 = ci[e + 3];
        const us8v v0 = *reinterpret_cast<const us8v*>(&Xp[(size_t)j0 * D_OUT + c8]);
        const us8v v1 = *reinterpret_cast<const us8v*>(&Xp[(size_t)j1 * D_OUT + c8]);
        const us8v v2 = *reinterpret_cast<const us8v*>(&Xp[(size_t)j2 * D_OUT + c8]);
        const us8v v3 = *reinterpret_cast<const us8v*>(&Xp[(size_t)j3 * D_OUT + c8]);
        #pragma unroll
        for (int j = 0; j < 8; ++j) {
            acc[j] += __uint_as_float((unsigned)v0[j] << 16);
            acc[j] += __uint_as_float((unsigned)v1[j] << 16);
            acc[j] += __uint_as_float((unsigned)v2[j] << 16);
            acc[j] += __uint_as_float((unsigned)v3[j] << 16);
        }
    }
    for (; e < e1; ++e) {
        const us8v v = *reinterpret_cast<const us8v*>(&Xp[(size_t)ci[e] * D_OUT + c8]);
        #pragma unroll
        for (int j = 0; j < 8; ++j)
            acc[j] += __uint_as_float((unsigned)v[j] << 16);
    }

    const float d = deg[node];
    float4 o0 = make_float4(acc[0] * d, acc[1] * d, acc[2] * d, acc[3] * d);
    float4 o1 = make_float4(acc[4] * d, acc[5] * d, acc[6] * d, acc[7] * d);
    float* op = out + (size_t)node * D_OUT + c8;
    *reinterpret_cast<float4*>(op)     = o0;
    *reinterpret_cast<float4*>(op + 4) = o1;
}

extern "C" void kernel_launch(void* const* d_in, const int* in_sizes, int n_in,
                              void* d_out, int out_size, void* d_ws, size_t ws_size,
                              hipStream_t stream)
{
    const float* X   = (const float*)d_in[0];
    const float* W   = (const float*)d_in[1];
    const int*   rp  = (const int*)d_in[2];
    const int*   ci  = (const int*)d_in[3];
    const float* deg = (const float*)d_in[4];
    float* out = (float*)d_out;
    unsigned short* Xp = (unsigned short*)d_ws;   // n * 64 bf16 = 12.8 MB

    const int n = in_sizes[4];   // N_NODES

    const int gemm_blocks = (n + 63) / 64;
    gemm_bf16_kernel<<<gemm_blocks, 256, 0, stream>>>(X, W, deg, Xp, n);

    const int agg_blocks = (n + 31) / 32;
    agg_kernel<<<agg_blocks, 256, 0, stream>>>(Xp, rp, ci, deg, out, n);
}